// Round 3
// baseline (309.334 us; speedup 1.0000x reference)
//
#include <hip/hip_runtime.h>

typedef unsigned short u16;
typedef __attribute__((ext_vector_type(8))) short bf16x8;
typedef __attribute__((ext_vector_type(4))) float f32x4;
typedef __attribute__((ext_vector_type(4))) unsigned short u16x4;

#define DM 1024

__device__ __forceinline__ float bf2f(u16 u){
  union { unsigned int i; float f; } v; v.i = ((unsigned int)u)<<16; return v.f;
}
__device__ __forceinline__ u16 f2bf(float f){
  unsigned int x = __float_as_uint(f);
  return (u16)((x + 0x7FFFu + ((x>>16)&1u)) >> 16);   // RNE, finite inputs only
}

// ---------------- K0: ternary-quantize the 4 weight matrices ----------------
__global__ __launch_bounds__(256)
void quantize_w(const float* __restrict__ W0, const float* __restrict__ W1,
                const float* __restrict__ W2, const float* __restrict__ W3,
                u16* __restrict__ wq, float* __restrict__ wsc)
{
  const int gr   = blockIdx.x*4 + (threadIdx.x>>6);  // global row 0..4095
  const int lane = threadIdx.x & 63;
  const int mat  = gr >> 10, row = gr & 1023;
  const float* W = (mat==0)?W0:(mat==1)?W1:(mat==2)?W2:W3;
  const float* wr = W + (size_t)row*DM;
  float4 v[4]; float s = 0.f;
  #pragma unroll
  for (int c=0;c<4;c++){
    v[c] = *(const float4*)&wr[c*256 + lane*4];
    s += fabsf(v[c].x)+fabsf(v[c].y)+fabsf(v[c].z)+fabsf(v[c].w);
  }
  #pragma unroll
  for (int off=32; off; off>>=1) s += __shfl_down(s, off);
  s = __shfl(s, 0);
  const float scale = fmaxf(s*(1.f/1024.f), 1e-5f);
  if (lane==0) wsc[gr] = scale;
  u16* wo = wq + (size_t)gr*DM;
  #pragma unroll
  for (int c=0;c<4;c++){
    u16x4 q;
    q[0] = f2bf(fminf(fmaxf(rintf(v[c].x/scale),-1.f),1.f));
    q[1] = f2bf(fminf(fmaxf(rintf(v[c].y/scale),-1.f),1.f));
    q[2] = f2bf(fminf(fmaxf(rintf(v[c].z/scale),-1.f),1.f));
    q[3] = f2bf(fminf(fmaxf(rintf(v[c].w/scale),-1.f),1.f));
    *(u16x4*)&wo[c*256 + lane*4] = q;
  }
}

// ---------------- K1: x f32 -> bf16 ----------------
__global__ void cvt_x(const float* __restrict__ x, u16* __restrict__ xb){
  const int i = (blockIdx.x*256 + threadIdx.x)*4;
  float4 v = *(const float4*)&x[i];
  u16x4 o; o[0]=f2bf(v.x); o[1]=f2bf(v.y); o[2]=f2bf(v.z); o[3]=f2bf(v.w);
  *(u16x4*)&xb[i] = o;
}

// ---------------- K2/K6: 256x256 deep-pipelined MFMA GEMM, BK=64, m201-style phases ----
// 8 waves (2M x 4N), per-wave C = 128x64. 2 LDS buffers, prefetch distance 2,
// per phase: {ds_reads; stage-issue; s_barrier; lgkmcnt(0); setprio MFMA x16; s_barrier}
// boundary: vmcnt(6) (+tail vmcnt(0) at last tile) + s_barrier (doubles as p3 trailer).
// Stage regions per tile t: p0: A(t+1) q1,q3 -> buf^1 | p1: B(t+2) q0,q1 -> buf |
//                           p2: A(t+2) q0,q2 -> buf   | p3: B(t+2) q2,q3 -> buf
// All write-after-read hazards separated by each wave's lgkmcnt(0) + a barrier.

__device__ __forceinline__ void stage_issue(const u16* __restrict__ gbase, int grow0,
                                            int tt, int q, u16* lbuf, int wave, int lane)
{
  const int r8    = lane>>3;            // 0..7 == (lrow & 7)
  const int lrow0 = q*64 + wave*8;      // wave-uniform row base (multiple of 8)
  const int colb  = (lane&7)<<4;
  const int scol  = colb ^ (r8<<4);     // pre-swizzled global source col (involution)
  const char* src = (const char*)(gbase + (size_t)(grow0 + lrow0 + r8)*DM) + tt*128 + scol;
  char* dst = (char*)lbuf + lrow0*128;  // linear LDS dest: HW adds lane*16
  __builtin_amdgcn_global_load_lds((const __attribute__((address_space(1))) void*)src,
                                   (__attribute__((address_space(3))) void*)dst, 16, 0, 0);
}

__device__ __forceinline__ bf16x8 ldsF(const u16* lbuf, int row, int ks, int lg){
  const int cb = ((ks<<6) + (lg<<4)) ^ ((row&7)<<4);
  return *(const bf16x8*)((const char*)lbuf + row*128 + cb);
}

__device__ __forceinline__ void barw(){   // converge, then drain LDS reads
  __builtin_amdgcn_sched_barrier(0);
  __builtin_amdgcn_s_barrier();
  asm volatile("s_waitcnt lgkmcnt(0)" ::: "memory");
  __builtin_amdgcn_sched_barrier(0);
}
__device__ __forceinline__ void bar2(){   // phase separator
  __builtin_amdgcn_sched_barrier(0);
  __builtin_amdgcn_s_barrier();
  __builtin_amdgcn_sched_barrier(0);
}

#define GPHASE(MI0, STAGE_STMT) { \
  bf16x8 a0k0 = ldsF(la, wm*128 + (MI0)*16   + lr, 0, lg); \
  bf16x8 a0k1 = ldsF(la, wm*128 + (MI0)*16   + lr, 1, lg); \
  bf16x8 a1k0 = ldsF(la, wm*128 + (MI0+1)*16 + lr, 0, lg); \
  bf16x8 a1k1 = ldsF(la, wm*128 + (MI0+1)*16 + lr, 1, lg); \
  STAGE_STMT; \
  barw(); \
  __builtin_amdgcn_s_setprio(1); \
  _Pragma("unroll") \
  for (int ni=0; ni<4; ++ni){ \
    acc[MI0][ni]   = __builtin_amdgcn_mfma_f32_16x16x32_bf16(a0k0, bf_[0][ni], acc[MI0][ni],   0,0,0); \
    acc[MI0][ni]   = __builtin_amdgcn_mfma_f32_16x16x32_bf16(a0k1, bf_[1][ni], acc[MI0][ni],   0,0,0); \
    acc[MI0+1][ni] = __builtin_amdgcn_mfma_f32_16x16x32_bf16(a1k0, bf_[0][ni], acc[MI0+1][ni], 0,0,0); \
    acc[MI0+1][ni] = __builtin_amdgcn_mfma_f32_16x16x32_bf16(a1k1, bf_[1][ni], acc[MI0+1][ni], 0,0,0); \
  } \
  __builtin_amdgcn_s_setprio(0); \
}

template<int MODE>
__global__ __launch_bounds__(512, 2)
void gemm_q8(const u16* __restrict__ A, const u16* __restrict__ Bq,
             const float* __restrict__ bscale,
             u16* __restrict__ o_r, u16* __restrict__ o_k, u16* __restrict__ o_v,
             float* __restrict__ o_f)
{
  __shared__ u16 sA[2][256*64];
  __shared__ u16 sB[2][256*64];
  const int tid = threadIdx.x, wave = tid>>6, lane = tid&63;
  const int lr = lane&15, lg = lane>>4;
  const int wm = wave>>2, wn = wave&3;
  const int bm0 = blockIdx.x*256, bn0 = blockIdx.y*256;
  const int nt = 16;                       // K = 1024 / BK=64

  f32x4 acc[8][4];
  #pragma unroll
  for (int i=0;i<8;i++)
    #pragma unroll
    for (int j=0;j<4;j++) acc[i][j] = (f32x4){0.f,0.f,0.f,0.f};

  // prologue: tile 0 fully [8]; tile 1 all but A q1,q3 [6] (those go at t=0 p0)
  #pragma unroll
  for (int q=0;q<4;q++){
    stage_issue(A,  bm0, 0, q, sA[0], wave, lane);
    stage_issue(Bq, bn0, 0, q, sB[0], wave, lane);
  }
  __builtin_amdgcn_sched_barrier(0);
  stage_issue(Bq, bn0, 1, 0, sB[1], wave, lane);
  stage_issue(Bq, bn0, 1, 1, sB[1], wave, lane);
  stage_issue(A,  bm0, 1, 0, sA[1], wave, lane);
  stage_issue(A,  bm0, 1, 2, sA[1], wave, lane);
  stage_issue(Bq, bn0, 1, 2, sB[1], wave, lane);
  stage_issue(Bq, bn0, 1, 3, sB[1], wave, lane);

  for (int t=0; t<nt; ++t){
    const int c = t&1;
    const u16* la = sA[c];
    const u16* lb = sB[c];
    // ---- tile boundary: counted wait (tail drains to 0), converge ----
    __builtin_amdgcn_sched_barrier(0);
    if (t < nt-1) asm volatile("s_waitcnt vmcnt(6)" ::: "memory");
    else          asm volatile("s_waitcnt vmcnt(0)" ::: "memory");
    __builtin_amdgcn_s_barrier();
    __builtin_amdgcn_sched_barrier(0);
    // ---- phase 0: read all 8 B-frags + A mi0,1; stage A(t+1) q1,q3 ----
    bf16x8 bf_[2][4];
    #pragma unroll
    for (int ks=0;ks<2;ks++)
      #pragma unroll
      for (int ni=0;ni<4;ni++)
        bf_[ks][ni] = ldsF(lb, wn*64 + ni*16 + lr, ks, lg);
    GPHASE(0, if (t+1<nt){ stage_issue(A,bm0,t+1,1,sA[c^1],wave,lane);
                           stage_issue(A,bm0,t+1,3,sA[c^1],wave,lane); } )
    bar2();
    GPHASE(2, if (t+2<nt){ stage_issue(Bq,bn0,t+2,0,sB[c],wave,lane);
                           stage_issue(Bq,bn0,t+2,1,sB[c],wave,lane); } )
    bar2();
    GPHASE(4, if (t+2<nt){ stage_issue(A,bm0,t+2,0,sA[c],wave,lane);
                           stage_issue(A,bm0,t+2,2,sA[c],wave,lane); } )
    bar2();
    GPHASE(6, if (t+2<nt){ stage_issue(Bq,bn0,t+2,2,sB[c],wave,lane);
                           stage_issue(Bq,bn0,t+2,3,sB[c],wave,lane); } )
    // p3's trailing barrier == next boundary barrier
  }

  // ---- epilogue ----
  #pragma unroll
  for (int mi=0; mi<8; ++mi){
    #pragma unroll
    for (int ni=0; ni<4; ++ni){
      const int col = bn0 + wn*64 + ni*16 + lr;
      const float sc = bscale[col];
      const int rowb = bm0 + wm*128 + mi*16 + lg*4;
      const f32x4 a = acc[mi][ni];
      if (MODE==0){
        const int seg = col>>10, d = col&1023;
        #pragma unroll
        for (int r2=0;r2<4;r2++){
          const size_t o = (size_t)(rowb+r2)*DM + d;
          const float val = a[r2]*sc;
          if (seg==0)      o_r[o] = f2bf(1.f/(1.f+expf(-val)));
          else if (seg==1) o_k[o] = f2bf(val);
          else             o_v[o] = f2bf(val);
        }
      } else {
        #pragma unroll
        for (int r2=0;r2<4;r2++)
          o_f[(size_t)(rowb+r2)*DM + col] = a[r2]*sc;
      }
    }
  }
}

// ---------------- K3: per-chunk sums of k*v / max(exp(t*ld),1e-10) (no materialization) ----
__global__ __launch_bounds__(256)
void kv_phase1(const u16* __restrict__ kb, const u16* __restrict__ vb,
               const float* __restrict__ decay, float* __restrict__ part)
{
  const int c = blockIdx.x & 63, b = blockIdx.x >> 6;
  const int d0 = threadIdx.x*4;
  float ld[4]; f32x4 sum = {0.f,0.f,0.f,0.f};
  #pragma unroll
  for (int j=0;j<4;j++){
    const float dec = 1.f/(1.f+expf(-decay[d0+j]));
    ld[j] = logf(fmaxf(dec, 1e-7f));
  }
  for (int t=c*64; t<c*64+64; ++t){
    const size_t base = ((size_t)(b*4096 + t))*DM + d0;
    const u16x4 k4 = *(const u16x4*)&kb[base];
    const u16x4 v4 = *(const u16x4*)&vb[base];
    const float tf = (float)t;
    #pragma unroll
    for (int j=0;j<4;j++){
      const float e = expf(tf*ld[j]);                        // underflows to 0 like ref
      sum[j] += bf2f(k4[j])*bf2f(v4[j]) / fmaxf(e, 1e-10f);
    }
  }
  *(f32x4*)&part[((size_t)(b*64+c))*DM + d0] = sum;
}

// ---------------- K4: exclusive prefix over the 64 chunk sums (8-wide pipelined) ------
__global__ void chunk_prefix(float* __restrict__ part){
  const int g = blockIdx.x*256 + threadIdx.x;  // 0..1023
  const int b = g >> 8, d0 = (g & 255)*4;
  f32x4 run = {0.f,0.f,0.f,0.f};
  for (int c8=0; c8<64; c8+=8){
    f32x4 v[8];
    #pragma unroll
    for (int i=0;i<8;i++)
      v[i] = *(const f32x4*)&part[((size_t)(b*64+c8+i))*DM + d0];
    #pragma unroll
    for (int i=0;i<8;i++){
      const f32x4 tmp = v[i];
      *(f32x4*)&part[((size_t)(b*64+c8+i))*DM + d0] = run;
      run += tmp;
    }
  }
}

// ---------------- K5: recompute scaled, in-chunk scan + y=r*state + rmsnorm -> yn ------
__global__ __launch_bounds__(256)
void scan_norm(const u16* __restrict__ kb, const u16* __restrict__ vb,
               const u16* __restrict__ rbuf, const float* __restrict__ part,
               const float* __restrict__ decay, const float* __restrict__ lnw,
               u16* __restrict__ yn)
{
  const int c = blockIdx.x & 63, b = blockIdx.x >> 6;
  const int tid = threadIdx.x, lane = tid&63, wave = tid>>6;
  const int d0 = tid*4;
  __shared__ float red[4];
  __shared__ float tot;
  f32x4 run = *(const f32x4*)&part[((size_t)(b*64+c))*DM + d0];
  float ld[4], lw[4];
  #pragma unroll
  for (int j=0;j<4;j++){
    const float dec = 1.f/(1.f+expf(-decay[d0+j]));
    ld[j] = logf(fmaxf(dec, 1e-7f));
    lw[j] = lnw[d0+j];
  }
  for (int t=c*64; t<c*64+64; ++t){
    const size_t base = ((size_t)(b*4096+t))*DM + d0;
    const u16x4 k4 = *(const u16x4*)&kb[base];
    const u16x4 v4 = *(const u16x4*)&vb[base];
    const u16x4 r4 = *(const u16x4*)&rbuf[base];
    const float tf = (float)t;
    float y[4]; float ss = 0.f;
    #pragma unroll
    for (int j=0;j<4;j++){
      const float e = expf(tf*ld[j]);                        // same expr as kv_phase1
      run[j] += bf2f(k4[j])*bf2f(v4[j]) / fmaxf(e, 1e-10f);
      const float st = run[j]*e;                             // unclipped, underflow like ref
      y[j] = bf2f(r4[j])*st;
      ss += y[j]*y[j];
    }
    #pragma unroll
    for (int off=32; off; off>>=1) ss += __shfl_down(ss, off);
    if (lane==0) red[wave] = ss;
    __syncthreads();
    if (tid==0) tot = (red[0]+red[1])+(red[2]+red[3]);
    __syncthreads();
    const float rs = 1.f/sqrtf(tot*(1.f/1024.f) + 1e-6f);
    u16x4 o;
    #pragma unroll
    for (int j=0;j<4;j++) o[j] = f2bf(y[j]*rs*lw[j]);
    *(u16x4*)&yn[base] = o;
  }
}

extern "C" void kernel_launch(void* const* d_in, const int* in_sizes, int n_in,
                              void* d_out, int out_size, void* d_ws, size_t ws_size,
                              hipStream_t stream)
{
  (void)in_sizes; (void)n_in; (void)out_size; (void)ws_size;
  const float* x    = (const float*)d_in[0];
  const float* Wr   = (const float*)d_in[1];
  const float* Wk   = (const float*)d_in[2];
  const float* Wv   = (const float*)d_in[3];
  const float* Wo   = (const float*)d_in[4];
  const float* dec  = (const float*)d_in[5];
  const float* lnw  = (const float*)d_in[6];

  char* ws = (char*)d_ws;
  u16*   wq     = (u16*)(ws + 0);
  float* wsc    = (float*)(ws + 8388608);
  u16*   rbuf   = (u16*)(ws + 8404992);
  u16*   kbuf   = (u16*)(ws + 41959424);
  u16*   vbuf   = (u16*)(ws + 75513856);
  float* part   = (float*)(ws + 109068288);
  u16*   xb     = (u16*)(ws + 110116864);
  u16*   yn     = kbuf;   // k consumed before K5 writes... NOTE: K5 reads kb while writing yn

  // yn must NOT alias kbuf anymore (scan_norm reads k per-t while writing yn at same base).
  // Same (b,t,d) slot: write happens after the read in-thread, but graph replay re-runs
  // scan_norm on already-overwritten kbuf -> WRONG. Use a fresh region instead.
  yn = (u16*)(ws + 143671296);   // past xb (33,554,432 bytes): [143,671,296 .. 177,225,728)

  quantize_w<<<1024, 256, 0, stream>>>(Wr, Wk, Wv, Wo, wq, wsc);
  cvt_x<<<16384, 256, 0, stream>>>(x, xb);
  gemm_q8<0><<<dim3(64,12), 512, 0, stream>>>(xb, wq, wsc, rbuf, kbuf, vbuf, nullptr);
  kv_phase1<<<256, 256, 0, stream>>>(kbuf, vbuf, dec, part);
  chunk_prefix<<<4, 256, 0, stream>>>(part);
  scan_norm<<<256, 256, 0, stream>>>(kbuf, vbuf, rbuf, part, dec, lnw, yn);
  gemm_q8<1><<<dim3(64,4), 512, 0, stream>>>(yn, wq + 3*1024*1024, wsc + 3072,
                                             nullptr, nullptr, nullptr, (float*)d_out);
}

// Round 4
// 250.608 us; speedup vs baseline: 1.2343x; 1.2343x over previous
//
#include <hip/hip_runtime.h>

typedef unsigned short u16;
typedef __attribute__((ext_vector_type(8))) short bf16x8;
typedef __attribute__((ext_vector_type(4))) float f32x4;
typedef __attribute__((ext_vector_type(4))) unsigned short u16x4;

#define DM 1024

__device__ __forceinline__ float bf2f(u16 u){
  union { unsigned int i; float f; } v; v.i = ((unsigned int)u)<<16; return v.f;
}
__device__ __forceinline__ u16 f2bf(float f){
  unsigned int x = __float_as_uint(f);
  return (u16)((x + 0x7FFFu + ((x>>16)&1u)) >> 16);   // RNE, finite inputs only
}

// ---------------- K0: ternary-quantize the 4 weight matrices ----------------
__global__ __launch_bounds__(256)
void quantize_w(const float* __restrict__ W0, const float* __restrict__ W1,
                const float* __restrict__ W2, const float* __restrict__ W3,
                u16* __restrict__ wq, float* __restrict__ wsc)
{
  const int gr   = blockIdx.x*4 + (threadIdx.x>>6);
  const int lane = threadIdx.x & 63;
  const int mat  = gr >> 10, row = gr & 1023;
  const float* W = (mat==0)?W0:(mat==1)?W1:(mat==2)?W2:W3;
  const float* wr = W + (size_t)row*DM;
  float4 v[4]; float s = 0.f;
  #pragma unroll
  for (int c=0;c<4;c++){
    v[c] = *(const float4*)&wr[c*256 + lane*4];
    s += fabsf(v[c].x)+fabsf(v[c].y)+fabsf(v[c].z)+fabsf(v[c].w);
  }
  #pragma unroll
  for (int off=32; off; off>>=1) s += __shfl_down(s, off);
  s = __shfl(s, 0);
  const float scale = fmaxf(s*(1.f/1024.f), 1e-5f);
  if (lane==0) wsc[gr] = scale;
  u16* wo = wq + (size_t)gr*DM;
  #pragma unroll
  for (int c=0;c<4;c++){
    u16x4 q;
    q[0] = f2bf(fminf(fmaxf(rintf(v[c].x/scale),-1.f),1.f));
    q[1] = f2bf(fminf(fmaxf(rintf(v[c].y/scale),-1.f),1.f));
    q[2] = f2bf(fminf(fmaxf(rintf(v[c].z/scale),-1.f),1.f));
    q[3] = f2bf(fminf(fmaxf(rintf(v[c].w/scale),-1.f),1.f));
    *(u16x4*)&wo[c*256 + lane*4] = q;
  }
}

// ---------------- K1: x f32 -> bf16 ----------------
__global__ void cvt_x(const float* __restrict__ x, u16* __restrict__ xb){
  const int i = (blockIdx.x*256 + threadIdx.x)*4;
  float4 v = *(const float4*)&x[i];
  u16x4 o; o[0]=f2bf(v.x); o[1]=f2bf(v.y); o[2]=f2bf(v.z); o[3]=f2bf(v.w);
  *(u16x4*)&xb[i] = o;
}

// ---------------- K2/K6: 256x256 GEMM, BK=64, read-pipelined 4-phase schedule -------
// Phase p: {issue reads for p+1; issue stages; counted lgkmcnt (guarantees p's regs);
//           16 MFMA on resident regs; barrier}. One vmcnt(4) per tile at p2-end
// (before the barrier, so ALL waves' stages are retired before p3's cross-tile reads).
// Stage plan: p0: A(t+1) q0..q3 -> sA[c^1]; p1: B(t+2) q0,q1 -> sB[c]; p2: B q2,q3.
// XOR swizzle (row&7)<<4 on stage source + ds_read (involution, rule 21).

#define SB0 __builtin_amdgcn_sched_barrier(0)
#define WL4  do{ asm volatile("s_waitcnt lgkmcnt(4)" ::: "memory"); SB0; }while(0)
#define WL12 do{ asm volatile("s_waitcnt lgkmcnt(12)" ::: "memory"); SB0; }while(0)
#define WL0  do{ asm volatile("s_waitcnt lgkmcnt(0)" ::: "memory"); SB0; }while(0)
#define VM4  do{ asm volatile("s_waitcnt vmcnt(4)" ::: "memory"); SB0; }while(0)
#define VM0  do{ asm volatile("s_waitcnt vmcnt(0)" ::: "memory"); SB0; }while(0)
#define BARR do{ SB0; __builtin_amdgcn_s_barrier(); SB0; }while(0)

#define STG(gB, off, T, Q, buf) \
  __builtin_amdgcn_global_load_lds( \
    (const __attribute__((address_space(1))) void*)((const char*)(gB) + (off) + (Q)*131072 + (T)*128), \
    (__attribute__((address_space(3))) void*)((char*)(buf) + ldst + (Q)*8192), 16, 0, 0)

#define RD(base, off) (*(const bf16x8*)((const char*)(base) + (off)))

#define MFMA16(AF, B, MI) \
  __builtin_amdgcn_s_setprio(1); \
  _Pragma("unroll") \
  for (int ni=0; ni<4; ++ni){ \
    acc[MI][ni]   = __builtin_amdgcn_mfma_f32_16x16x32_bf16(AF[0], B[ni],   acc[MI][ni],   0,0,0); \
    acc[MI][ni]   = __builtin_amdgcn_mfma_f32_16x16x32_bf16(AF[1], B[4+ni], acc[MI][ni],   0,0,0); \
    acc[MI+1][ni] = __builtin_amdgcn_mfma_f32_16x16x32_bf16(AF[2], B[ni],   acc[MI+1][ni], 0,0,0); \
    acc[MI+1][ni] = __builtin_amdgcn_mfma_f32_16x16x32_bf16(AF[3], B[4+ni], acc[MI+1][ni], 0,0,0); \
  } \
  __builtin_amdgcn_s_setprio(0)

#define TILE(T, C, BCUR, BNXT) { \
  const char* la  = (const char*)sA[C]; \
  const char* lnA = (const char*)sA[(C)^1]; \
  const char* lnB = (const char*)sB[(C)^1]; \
  /* P0: read ay=mi2,3 ; stage A(T+1) */ \
  ay[0]=RD(la, arow+2*2048+koff0); ay[1]=RD(la, arow+2*2048+koff1); \
  ay[2]=RD(la, arow+3*2048+koff0); ay[3]=RD(la, arow+3*2048+koff1); \
  if ((T)+1<nt){ STG(Ag, aoff, (T)+1, 0, sA[(C)^1]); STG(Ag, aoff, (T)+1, 1, sA[(C)^1]); \
                 STG(Ag, aoff, (T)+1, 2, sA[(C)^1]); STG(Ag, aoff, (T)+1, 3, sA[(C)^1]); } \
  WL4; MFMA16(ax, BCUR, 0); BARR; \
  /* P1: read ax=mi4,5 ; stage B(T+2) q0,q1 */ \
  ax[0]=RD(la, arow+4*2048+koff0); ax[1]=RD(la, arow+4*2048+koff1); \
  ax[2]=RD(la, arow+5*2048+koff0); ax[3]=RD(la, arow+5*2048+koff1); \
  if ((T)+2<nt){ STG(Bg, boff, (T)+2, 0, sB[C]); STG(Bg, boff, (T)+2, 1, sB[C]); } \
  WL4; MFMA16(ay, BCUR, 2); BARR; \
  /* P2: read ay=mi6,7 ; stage B(T+2) q2,q3 ; per-tile vmcnt BEFORE barrier */ \
  ay[0]=RD(la, arow+6*2048+koff0); ay[1]=RD(la, arow+6*2048+koff1); \
  ay[2]=RD(la, arow+7*2048+koff0); ay[3]=RD(la, arow+7*2048+koff1); \
  if ((T)+2<nt){ STG(Bg, boff, (T)+2, 2, sB[C]); STG(Bg, boff, (T)+2, 3, sB[C]); } \
  WL4; MFMA16(ax, BCUR, 4); SB0; \
  if ((T)==nt-2) { VM0; } else if ((T)<nt-2) { VM4; } \
  BARR; \
  /* P3: prefetch next tile's B (8) + A mi0,1 (4) ; counted wait ; MFMA mi6,7 */ \
  if ((T)<nt-1){ \
    BNXT[0]=RD(lnB, brow+0*2048+koff0); BNXT[1]=RD(lnB, brow+1*2048+koff0); \
    BNXT[2]=RD(lnB, brow+2*2048+koff0); BNXT[3]=RD(lnB, brow+3*2048+koff0); \
    BNXT[4]=RD(lnB, brow+0*2048+koff1); BNXT[5]=RD(lnB, brow+1*2048+koff1); \
    BNXT[6]=RD(lnB, brow+2*2048+koff1); BNXT[7]=RD(lnB, brow+3*2048+koff1); \
    ax[0]=RD(lnA, arow+0*2048+koff0); ax[1]=RD(lnA, arow+0*2048+koff1); \
    ax[2]=RD(lnA, arow+1*2048+koff0); ax[3]=RD(lnA, arow+1*2048+koff1); \
    WL12; \
  } else { WL0; } \
  MFMA16(ay, BCUR, 6); BARR; \
}

template<int MODE>
__global__ __launch_bounds__(512, 2)
void gemm_p(const u16* __restrict__ Ag, const u16* __restrict__ Bg,
            const float* __restrict__ bscale,
            u16* __restrict__ o_r, u16* __restrict__ o_k, u16* __restrict__ o_v,
            float* __restrict__ o_f)
{
  __shared__ u16 sA[2][256*64];
  __shared__ u16 sB[2][256*64];
  const int tid = threadIdx.x, wave = tid>>6, lane = tid&63;
  const int lr = lane&15, lg = lane>>4;
  const int wm = wave>>2, wn = wave&3;
  const int bm0 = blockIdx.x*256, bn0 = blockIdx.y*256;
  constexpr int nt = 16;                        // K = 1024 / 64

  // staging addresses
  const int r8   = lane>>3;
  const int scol = ((lane&7)<<4) ^ (r8<<4);     // pre-swizzled source col (bytes)
  const size_t aoff = (size_t)(bm0 + wave*8 + r8)*2048 + scol;
  const size_t boff = (size_t)(bn0 + wave*8 + r8)*2048 + scol;
  const int ldst = wave*1024;                   // LDS dest base (+q*8192)
  // ds_read addresses
  const int S = (lr&7)<<4;
  const int koff0 = (0  + (lg<<4)) ^ S;
  const int koff1 = (64 + (lg<<4)) ^ S;
  const int arow = (wm*128 + lr)*128;           // + mi*2048
  const int brow = (wn*64  + lr)*128;           // + ni*2048

  f32x4 acc[8][4];
  #pragma unroll
  for (int i=0;i<8;i++)
    #pragma unroll
    for (int j=0;j<4;j++) acc[i][j] = (f32x4){0.f,0.f,0.f,0.f};

  bf16x8 bc[8], bn2[8], ax[4], ay[4];

  // prologue: stage A(0),B(0) -> bufs[0]; B(1) -> sB[1]
  #pragma unroll
  for (int q=0;q<4;q++){ STG(Ag, aoff, 0, q, sA[0]); STG(Bg, boff, 0, q, sB[0]); }
  #pragma unroll
  for (int q=0;q<4;q++){ STG(Bg, boff, 1, q, sB[1]); }
  VM4;                                          // A(0),B(0) landed (B(1) in flight)
  BARR;                                         // every wave's stages retired
  {
    const char* la0 = (const char*)sA[0];
    const char* lb0 = (const char*)sB[0];
    bc[0]=RD(lb0, brow+0*2048+koff0); bc[1]=RD(lb0, brow+1*2048+koff0);
    bc[2]=RD(lb0, brow+2*2048+koff0); bc[3]=RD(lb0, brow+3*2048+koff0);
    bc[4]=RD(lb0, brow+0*2048+koff1); bc[5]=RD(lb0, brow+1*2048+koff1);
    bc[6]=RD(lb0, brow+2*2048+koff1); bc[7]=RD(lb0, brow+3*2048+koff1);
    ax[0]=RD(la0, arow+0*2048+koff0); ax[1]=RD(la0, arow+0*2048+koff1);
    ax[2]=RD(la0, arow+1*2048+koff0); ax[3]=RD(la0, arow+1*2048+koff1);
  }
  for (int tp=0; tp<nt; tp+=2){
    TILE(tp,   0, bc, bn2)
    TILE(tp+1, 1, bn2, bc)
  }

  // ---- epilogue ----
  #pragma unroll
  for (int mi=0; mi<8; ++mi){
    #pragma unroll
    for (int ni=0; ni<4; ++ni){
      const int col = bn0 + wn*64 + ni*16 + lr;
      const float sc = bscale[col];
      const int rowb = bm0 + wm*128 + mi*16 + lg*4;
      const f32x4 a = acc[mi][ni];
      if (MODE==0){
        const int seg = col>>10, d = col&1023;
        #pragma unroll
        for (int r2=0;r2<4;r2++){
          const size_t o = (size_t)(rowb+r2)*DM + d;
          const float val = a[r2]*sc;
          if (seg==0)      o_r[o] = f2bf(1.f/(1.f+expf(-val)));
          else if (seg==1) o_k[o] = f2bf(val);
          else             o_v[o] = f2bf(val);
        }
      } else {
        #pragma unroll
        for (int r2=0;r2<4;r2++)
          o_f[(size_t)(rowb+r2)*DM + col] = a[r2]*sc;
      }
    }
  }
}

// ---------------- K3: per-chunk sums of k*v / max(exp(t*ld),1e-10), CH=32 ----------
__global__ __launch_bounds__(256)
void kv_phase1(const u16* __restrict__ kb, const u16* __restrict__ vb,
               const float* __restrict__ decay, float* __restrict__ part)
{
  const int c = blockIdx.x & 127, b = blockIdx.x >> 7;
  const int d0 = threadIdx.x*4;
  float ld[4]; f32x4 sum = {0.f,0.f,0.f,0.f};
  #pragma unroll
  for (int j=0;j<4;j++){
    const float dec = 1.f/(1.f+expf(-decay[d0+j]));
    ld[j] = logf(fmaxf(dec, 1e-7f));
  }
  for (int t=c*32; t<c*32+32; ++t){
    const size_t base = ((size_t)(b*4096 + t))*DM + d0;
    const u16x4 k4 = *(const u16x4*)&kb[base];
    const u16x4 v4 = *(const u16x4*)&vb[base];
    const float tf = (float)t;
    #pragma unroll
    for (int j=0;j<4;j++){
      const float e = expf(tf*ld[j]);                        // underflows to 0 like ref
      sum[j] += bf2f(k4[j])*bf2f(v4[j]) / fmaxf(e, 1e-10f);
    }
  }
  *(f32x4*)&part[((size_t)(b*128+c))*DM + d0] = sum;
}

// ---------------- K4: exclusive prefix over 128 chunk sums (8-wide pipelined) -------
__global__ void chunk_prefix(float* __restrict__ part){
  const int g = blockIdx.x*256 + threadIdx.x;  // 0..1023
  const int b = g >> 8, d0 = (g & 255)*4;
  f32x4 run = {0.f,0.f,0.f,0.f};
  for (int c8=0; c8<128; c8+=8){
    f32x4 v[8];
    #pragma unroll
    for (int i=0;i<8;i++)
      v[i] = *(const f32x4*)&part[((size_t)(b*128+c8+i))*DM + d0];
    #pragma unroll
    for (int i=0;i<8;i++){
      const f32x4 tmp = v[i];
      *(f32x4*)&part[((size_t)(b*128+c8+i))*DM + d0] = run;
      run += tmp;
    }
  }
}

// ---------------- K5: recompute scaled, in-chunk scan + rmsnorm -> yn (CH=32) -------
__global__ __launch_bounds__(256)
void scan_norm(const u16* __restrict__ kb, const u16* __restrict__ vb,
               const u16* __restrict__ rbuf, const float* __restrict__ part,
               const float* __restrict__ decay, const float* __restrict__ lnw,
               u16* __restrict__ yn)
{
  const int c = blockIdx.x & 127, b = blockIdx.x >> 7;
  const int tid = threadIdx.x, lane = tid&63, wave = tid>>6;
  const int d0 = tid*4;
  __shared__ float red[2][4];
  f32x4 run = *(const f32x4*)&part[((size_t)(b*128+c))*DM + d0];
  float ld[4], lw[4];
  #pragma unroll
  for (int j=0;j<4;j++){
    const float dec = 1.f/(1.f+expf(-decay[d0+j]));
    ld[j] = logf(fmaxf(dec, 1e-7f));
    lw[j] = lnw[d0+j];
  }
  for (int t=c*32; t<c*32+32; ++t){
    const size_t base = ((size_t)(b*4096+t))*DM + d0;
    const u16x4 k4 = *(const u16x4*)&kb[base];
    const u16x4 v4 = *(const u16x4*)&vb[base];
    const u16x4 r4 = *(const u16x4*)&rbuf[base];
    const float tf = (float)t;
    float y[4]; float ss = 0.f;
    #pragma unroll
    for (int j=0;j<4;j++){
      const float e = expf(tf*ld[j]);                        // same expr as kv_phase1
      run[j] += bf2f(k4[j])*bf2f(v4[j]) / fmaxf(e, 1e-10f);
      const float st = run[j]*e;                             // unclipped, underflows like ref
      y[j] = bf2f(r4[j])*st;
      ss += y[j]*y[j];
    }
    #pragma unroll
    for (int off=32; off; off>>=1) ss += __shfl_down(ss, off);
    if (lane==0) red[t&1][wave] = ss;
    __builtin_amdgcn_s_barrier();
    const float tot = (red[t&1][0]+red[t&1][1])+(red[t&1][2]+red[t&1][3]);
    const float rs = 1.f/sqrtf(tot*(1.f/1024.f) + 1e-6f);
    u16x4 o;
    #pragma unroll
    for (int j=0;j<4;j++) o[j] = f2bf(y[j]*rs*lw[j]);
    *(u16x4*)&yn[base] = o;
  }
}

extern "C" void kernel_launch(void* const* d_in, const int* in_sizes, int n_in,
                              void* d_out, int out_size, void* d_ws, size_t ws_size,
                              hipStream_t stream)
{
  (void)in_sizes; (void)n_in; (void)out_size; (void)ws_size;
  const float* x    = (const float*)d_in[0];
  const float* Wr   = (const float*)d_in[1];
  const float* Wk   = (const float*)d_in[2];
  const float* Wv   = (const float*)d_in[3];
  const float* Wo   = (const float*)d_in[4];
  const float* dec  = (const float*)d_in[5];
  const float* lnw  = (const float*)d_in[6];

  // layout: wq 8MB | wsc | rbuf 33.5MB | kbuf 33.5MB | vbuf 33.5MB | part 2MB | xb 33.5MB
  //         yn aliases xb (xb dead after GEMM1, yn written by K5, read by GEMM2)
  char* ws = (char*)d_ws;
  u16*   wq     = (u16*)(ws + 0);
  float* wsc    = (float*)(ws + 8388608);
  u16*   rbuf   = (u16*)(ws + 8404992);
  u16*   kbuf   = (u16*)(ws + 41959424);
  u16*   vbuf   = (u16*)(ws + 75513856);
  float* part   = (float*)(ws + 109068288);   // [109068288, 111165440) = 2MB
  u16*   xb     = (u16*)(ws + 111165440);     // [111165440, 144719872)
  u16*   yn     = xb;

  quantize_w<<<1024, 256, 0, stream>>>(Wr, Wk, Wv, Wo, wq, wsc);
  cvt_x<<<16384, 256, 0, stream>>>(x, xb);
  gemm_p<0><<<dim3(64,12), 512, 0, stream>>>(xb, wq, wsc, rbuf, kbuf, vbuf, nullptr);
  kv_phase1<<<512, 256, 0, stream>>>(kbuf, vbuf, dec, part);
  chunk_prefix<<<4, 256, 0, stream>>>(part);
  scan_norm<<<512, 256, 0, stream>>>(kbuf, vbuf, rbuf, part, dec, lnw, yn);
  gemm_p<1><<<dim3(64,4), 512, 0, stream>>>(yn, wq + 3*1024*1024, wsc + 3072,
                                            nullptr, nullptr, nullptr, (float*)d_out);
}